// Round 1
// baseline (4611.039 us; speedup 1.0000x reference)
//
#include <hip/hip_runtime.h>
#include <cstdint>
#include <cstddef>

typedef unsigned short u16;
typedef __attribute__((ext_vector_type(8))) short short8;
typedef __attribute__((ext_vector_type(4))) float f32x4;

// B=512, T=64, D=16, H=1024 ; 4H=4096
#define NB 512
#define NT 64
#define ND 16
#define NH 1024

__device__ __forceinline__ u16 f2bf(float x) {
  union { float f; unsigned u; } v; v.f = x;
  unsigned r = v.u + 0x7fffu + ((v.u >> 16) & 1u);
  return (u16)(r >> 16);
}
__device__ __forceinline__ float sigf(float x) { return 1.f / (1.f + __expf(-x)); }

__device__ __forceinline__ void glds16(const void* g, void* l) {
  __builtin_amdgcn_global_load_lds((const __attribute__((address_space(1))) void*)g,
                                   (__attribute__((address_space(3))) void*)l, 16, 0, 0);
}

// n' = (h/16)*64 + gate*16 + (h%16)  ->  orig row = gate*1024 + h
__device__ __forceinline__ int inv_np(int np) {
  int hb = np >> 6, g = (np >> 4) & 3, hlo = np & 15;
  return g * 1024 + hb * 16 + hlo;
}

// ---------------- prep: big weight matrices (K=1024) -> bf16 reordered ----------------
__global__ void k_prep_big(const float* s0, const float* s1, const float* s2,
                           const float* s3, const float* s4, const float* s5, u16* dst) {
  for (unsigned q = blockIdx.x * 256 + threadIdx.x; q < (6u << 20); q += gridDim.x * 256) {
    int mat = q >> 20;
    int rem = q & ((1 << 20) - 1);
    int np = rem >> 8;            // 0..4095
    int k = (rem & 255) * 4;      // 0..1020
    int row = inv_np(np);
    const float* s = mat == 0 ? s0 : mat == 1 ? s1 : mat == 2 ? s2 : mat == 3 ? s3 : mat == 4 ? s4 : s5;
    float4 v = *(const float4*)(s + (size_t)row * NH + k);
    u16* d = dst + (size_t)mat * 4194304 + (size_t)np * NH + k;
    d[0] = f2bf(v.x); d[1] = f2bf(v.y); d[2] = f2bf(v.z); d[3] = f2bf(v.w);
  }
}

// ---------------- prep: Wih0 padded to K=32, combined biases ----------------
__global__ void k_prep_small(const float* fwih0, const float* bwih0,
                             const float* fbi0, const float* fbh0, const float* fbi1, const float* fbh1,
                             const float* bbi0, const float* bbh0, const float* bbi1, const float* bbh1,
                             u16* wih0p, float* biasb) {
  int idx = blockIdx.x * 256 + threadIdx.x;
  if (idx < 262144) {
    int dir = idx >> 17;
    int r = idx & 131071;
    int np = r >> 5, d = r & 31;
    int row = inv_np(np);
    const float* s = dir ? bwih0 : fwih0;
    float v = (d < 16) ? s[row * 16 + d] : 0.f;
    wih0p[(size_t)dir * 131072 + r] = f2bf(v);
  } else if (idx < 262144 + 16384) {
    int j = idx - 262144;
    int which = j >> 12;  // 0 fw-l0, 1 fw-l1, 2 bw-l0, 3 bw-l1
    int np = j & 4095;
    int row = inv_np(np);
    const float* bi = which == 0 ? fbi0 : which == 1 ? fbi1 : which == 2 ? bbi0 : bbi1;
    const float* bh = which == 0 ? fbh0 : which == 1 ? fbh1 : which == 2 ? bbh0 : bbh1;
    biasb[which * 4096 + np] = bi[row] + bh[row];
  }
}

// ---------------- init: pre-loop layer-1 cell from biases; zero layer-0 state ----------------
__global__ void k_init(const float* fbi1, const float* fbh1, const float* bbi1, const float* bbh1,
                       float* c0, float* c1, float* h1f, u16* h0bf, u16* h1bf) {
  int idx = blockIdx.x * 256 + threadIdx.x;  // 2*512*1024 exact
  int dir = idx >> 19;
  int rem = idx & ((1 << 19) - 1);
  int h = rem & (NH - 1);
  const float* bi = dir ? bbi1 : fbi1;
  const float* bh = dir ? bbh1 : fbh1;
  float gi = bi[h] + bh[h];
  float gg = bi[2048 + h] + bh[2048 + h];
  float go = bi[3072 + h] + bh[3072 + h];
  float c = sigf(gi) * tanhf(gg);
  float hv = sigf(go) * tanhf(c);
  size_t o = (size_t)dir * 524288 + rem;
  c1[o] = c;
  h1f[o] = hv;
  h1bf[(size_t)(dir * 2) * 524288 + rem] = f2bf(hv);  // buf 0
  c0[o] = 0.f;
  h0bf[(size_t)(dir * 2) * 524288 + rem] = 0;         // buf 0
}

// ---------------- cc: (1-m)*(h1 @ out_W^T + out_b) + m*x  -> bf16, K padded to 32 ----------------
__global__ __launch_bounds__(256) void k_cc(const float* values, const float* masks,
                                            const float* outW, const float* outb,
                                            const float* hf1, const float* hb1,
                                            u16* ccbf, int t) {
  int dir = blockIdx.y;
  int w = threadIdx.x >> 6, lane = threadIdx.x & 63;
  int b = blockIdx.x * 4 + w;
  const float* h1 = dir ? hb1 : hf1;
  int tt = dir ? (NT - 1 - t) : t;
  const float4* hrow = (const float4*)(h1 + (size_t)b * NH);
  float4 hv[4];
#pragma unroll
  for (int j = 0; j < 4; ++j) hv[j] = hrow[lane + 64 * j];
  float sums[16];
#pragma unroll
  for (int d = 0; d < 16; ++d) {
    const float4* wrow = (const float4*)(outW + d * NH);
    float s = 0.f;
#pragma unroll
    for (int j = 0; j < 4; ++j) {
      float4 wv = wrow[lane + 64 * j];
      s += hv[j].x * wv.x + hv[j].y * wv.y + hv[j].z * wv.z + hv[j].w * wv.w;
    }
#pragma unroll
    for (int off = 32; off; off >>= 1) s += __shfl_xor(s, off);
    sums[d] = s;
  }
  if (lane == 0) {
    u16* dst = ccbf + ((size_t)dir * 512 + b) * 32;
    const float* xv = values + ((size_t)b * NT + tt) * ND;
    const float* mv = masks + ((size_t)b * NT + tt) * ND;
#pragma unroll
    for (int d = 0; d < 16; ++d) {
      float m = mv[d];
      float cc = (1.f - m) * (sums[d] + outb[d]) + m * xv[d];
      dst[d] = f2bf(cc);
    }
#pragma unroll
    for (int d = 16; d < 32; ++d) dst[d] = 0;
  }
}

// ---------------- fused GEMM (2 A/W pairs) + LSTM cell epilogue ----------------
// gates(512x4096, gate-interleaved cols) = A0@W0^T + A1@W1^T + bias; then cell vs c_st.
struct GemmCellArgs {
  const u16* A0[2]; const u16* W0[2];
  const u16* A1[2]; const u16* W1[2];
  const float* bias[2];
  float* c_st[2];
  float* h_st[2];   // may be null
  u16* h_out[2];
  int nk1; int s1;  // pair-1 chunk count and row stride (A and W share it)
};

__global__ __launch_bounds__(256) void k_gemm_cell(GemmCellArgs ar) {
  const int dir = blockIdx.z;
  const int tid = threadIdx.x, w = tid >> 6, lane = tid & 63;
  const int m0 = blockIdx.y * 64, n0 = blockIdx.x * 128;

  __shared__ __align__(16) u16 At[64 * 32];
  __shared__ __align__(16) u16 Bt[128 * 32];

  f32x4 acc[2][4];
#pragma unroll
  for (int i = 0; i < 2; ++i)
#pragma unroll
    for (int j = 0; j < 4; ++j) acc[i][j] = f32x4{0.f, 0.f, 0.f, 0.f};

  const int srow = lane >> 2, scol = (lane & 3) * 8;
  const int wm = w >> 1, wn = w & 1;
  const u16* fA = &At[(wm * 32 + (lane & 15)) * 32 + (lane >> 4) * 8];
  const u16* fB = &Bt[(wn * 64 + (lane & 15)) * 32 + (lane >> 4) * 8];
  u16* lA = &At[w * 512];
  u16* lB0 = &Bt[w * 1024];
  u16* lB1 = &Bt[w * 1024 + 512];

  // ---- pair 0: K = 1024 (strides fixed at 1024) ----
  {
    const u16* gA = ar.A0[dir] + (size_t)(m0 + w * 16 + srow) * NH + scol;
    const u16* gB0 = ar.W0[dir] + (size_t)(n0 + w * 32 + srow) * NH + scol;
    const u16* gB1 = gB0 + 16 * NH;
    for (int kc = 0; kc < 32; ++kc) {
      glds16(gA + kc * 32, lA);
      glds16(gB0 + kc * 32, lB0);
      glds16(gB1 + kc * 32, lB1);
      __syncthreads();
      short8 a[2], bb[4];
#pragma unroll
      for (int mi = 0; mi < 2; ++mi) a[mi] = *(const short8*)(fA + mi * 16 * 32);
#pragma unroll
      for (int ni = 0; ni < 4; ++ni) bb[ni] = *(const short8*)(fB + ni * 16 * 32);
#pragma unroll
      for (int mi = 0; mi < 2; ++mi)
#pragma unroll
        for (int ni = 0; ni < 4; ++ni)
          acc[mi][ni] = __builtin_amdgcn_mfma_f32_16x16x32_bf16(a[mi], bb[ni], acc[mi][ni], 0, 0, 0);
      __syncthreads();
    }
  }
  // ---- pair 1: K = 32*nk1, stride s1 ----
  {
    const int s1 = ar.s1;
    const u16* gA = ar.A1[dir] + (size_t)(m0 + w * 16 + srow) * s1 + scol;
    const u16* gB0 = ar.W1[dir] + (size_t)(n0 + w * 32 + srow) * s1 + scol;
    const u16* gB1 = ar.W1[dir] + (size_t)(n0 + w * 32 + 16 + srow) * s1 + scol;
    for (int kc = 0; kc < ar.nk1; ++kc) {
      glds16(gA + kc * 32, lA);
      glds16(gB0 + kc * 32, lB0);
      glds16(gB1 + kc * 32, lB1);
      __syncthreads();
      short8 a[2], bb[4];
#pragma unroll
      for (int mi = 0; mi < 2; ++mi) a[mi] = *(const short8*)(fA + mi * 16 * 32);
#pragma unroll
      for (int ni = 0; ni < 4; ++ni) bb[ni] = *(const short8*)(fB + ni * 16 * 32);
#pragma unroll
      for (int mi = 0; mi < 2; ++mi)
#pragma unroll
        for (int ni = 0; ni < 4; ++ni)
          acc[mi][ni] = __builtin_amdgcn_mfma_f32_16x16x32_bf16(a[mi], bb[ni], acc[mi][ni], 0, 0, 0);
      __syncthreads();
    }
  }

  // ---- epilogue: bias + LSTM cell; each (row,h) owned by exactly one lane ----
  const float* bias = ar.bias[dir];
  float* cs = ar.c_st[dir];
  float* hs = ar.h_st[dir];
  u16* ho = ar.h_out[dir];
  const int u = lane & 15;
  const int hg = ((n0 + wn * 64) >> 2) + u;  // hidden unit index
  const float b0 = bias[n0 + wn * 64 + u];
  const float b1 = bias[n0 + wn * 64 + 16 + u];
  const float b2 = bias[n0 + wn * 64 + 32 + u];
  const float b3 = bias[n0 + wn * 64 + 48 + u];
#pragma unroll
  for (int mi = 0; mi < 2; ++mi)
#pragma unroll
    for (int r = 0; r < 4; ++r) {
      int row = m0 + wm * 32 + mi * 16 + ((lane >> 4) << 2) + r;
      size_t sidx = (size_t)row * NH + hg;
      float iv = acc[mi][0][r] + b0;
      float fv = acc[mi][1][r] + b1;
      float gv = acc[mi][2][r] + b2;
      float ov = acc[mi][3][r] + b3;
      float cp = cs[sidx];
      float c2 = sigf(fv) * cp + sigf(iv) * tanhf(gv);
      float hv = sigf(ov) * tanhf(c2);
      cs[sidx] = c2;
      if (hs) hs[sidx] = hv;
      ho[sidx] = f2bf(hv);
    }
}

// ---------------- final outputs ----------------
__global__ void k_final(const float* hf1, const float* hb1, const float* values,
                        const float* masks, float* out) {
  int idx = blockIdx.x * 256 + threadIdx.x;  // 524288 exact
  int b = idx >> 10, j = idx & 1023;
  float hf = hf1[idx];
  float hb = hb1[(size_t)b * NH + (NH - 1 - j)];
  float hv = 0.5f * (hf + hb);
  float m = masks[idx];
  out[idx] = hv;
  out[524288 + idx] = hv;
  out[1048576 + idx] = hv * (1.f - m) + values[idx] * m;
}

extern "C" void kernel_launch(void* const* d_in, const int* in_sizes, int n_in,
                              void* d_out, int out_size, void* d_ws, size_t ws_size,
                              hipStream_t stream) {
  const float* values  = (const float*)d_in[0];
  const float* masks   = (const float*)d_in[1];
  const float* fw_Wih0 = (const float*)d_in[2];
  const float* fw_Whh0 = (const float*)d_in[3];
  const float* fw_bih0 = (const float*)d_in[4];
  const float* fw_bhh0 = (const float*)d_in[5];
  const float* fw_Wih1 = (const float*)d_in[6];
  const float* fw_Whh1 = (const float*)d_in[7];
  const float* fw_bih1 = (const float*)d_in[8];
  const float* fw_bhh1 = (const float*)d_in[9];
  const float* bw_Wih0 = (const float*)d_in[10];
  const float* bw_Whh0 = (const float*)d_in[11];
  const float* bw_bih0 = (const float*)d_in[12];
  const float* bw_bhh0 = (const float*)d_in[13];
  const float* bw_Wih1 = (const float*)d_in[14];
  const float* bw_Whh1 = (const float*)d_in[15];
  const float* bw_bih1 = (const float*)d_in[16];
  const float* bw_bhh1 = (const float*)d_in[17];
  const float* out_W   = (const float*)d_in[18];
  const float* out_b   = (const float*)d_in[19];

  char* ws = (char*)d_ws;
  u16* wbig    = (u16*)ws;                    // 6 x 4M u16 (fwWhh0,fwWih1,fwWhh1,bwWhh0,bwWih1,bwWhh1)
  u16* wih0p   = (u16*)(ws + 50331648);       // 2 x 4096x32
  float* biasb = (float*)(ws + 50855936);     // 4 x 4096
  float* c0    = (float*)(ws + 50921472);     // 2 x 512x1024 f32
  float* c1    = (float*)(ws + 55115776);
  float* h1f   = (float*)(ws + 59310080);
  u16* h0bf    = (u16*)(ws + 63504384);       // [dir][pingpong] x 512x1024 bf16
  u16* h1bf    = (u16*)(ws + 67698688);
  u16* ccbf    = (u16*)(ws + 71892992);       // 2 x 512x32
  if (ws_size < 71958528) return;

  k_prep_big<<<4096, 256, 0, stream>>>(fw_Whh0, fw_Wih1, fw_Whh1, bw_Whh0, bw_Wih1, bw_Whh1, wbig);
  k_prep_small<<<1088, 256, 0, stream>>>(fw_Wih0, bw_Wih0, fw_bih0, fw_bhh0, fw_bih1, fw_bhh1,
                                         bw_bih0, bw_bhh0, bw_bih1, bw_bhh1, wih0p, biasb);
  k_init<<<4096, 256, 0, stream>>>(fw_bih1, fw_bhh1, bw_bih1, bw_bhh1, c0, c1, h1f, h0bf, h1bf);

  for (int t = 0; t < NT; ++t) {
    int p = t & 1;
    k_cc<<<dim3(128, 2), 256, 0, stream>>>(values, masks, out_W, out_b, h1f, h1f + 524288, ccbf, t);

    GemmCellArgs a0;
    for (int d = 0; d < 2; ++d) {
      a0.A0[d] = h0bf + (size_t)(d * 2 + p) * 524288;
      a0.W0[d] = wbig + (size_t)(d * 3 + 0) * 4194304;
      a0.A1[d] = ccbf + (size_t)d * 16384;
      a0.W1[d] = wih0p + (size_t)d * 131072;
      a0.bias[d] = biasb + (d * 2 + 0) * 4096;
      a0.c_st[d] = c0 + (size_t)d * 524288;
      a0.h_st[d] = nullptr;
      a0.h_out[d] = h0bf + (size_t)(d * 2 + (1 - p)) * 524288;
    }
    a0.nk1 = 1; a0.s1 = 32;
    k_gemm_cell<<<dim3(32, 8, 2), 256, 0, stream>>>(a0);

    GemmCellArgs a1;
    for (int d = 0; d < 2; ++d) {
      a1.A0[d] = h0bf + (size_t)(d * 2 + (1 - p)) * 524288;
      a1.W0[d] = wbig + (size_t)(d * 3 + 1) * 4194304;
      a1.A1[d] = h1bf + (size_t)(d * 2 + p) * 524288;
      a1.W1[d] = wbig + (size_t)(d * 3 + 2) * 4194304;
      a1.bias[d] = biasb + (d * 2 + 1) * 4096;
      a1.c_st[d] = c1 + (size_t)d * 524288;
      a1.h_st[d] = h1f + (size_t)d * 524288;
      a1.h_out[d] = h1bf + (size_t)(d * 2 + (1 - p)) * 524288;
    }
    a1.nk1 = 32; a1.s1 = 1024;
    k_gemm_cell<<<dim3(32, 8, 2), 256, 0, stream>>>(a1);
  }

  k_final<<<2048, 256, 0, stream>>>(h1f, h1f + 524288, values, masks, (float*)d_out);
}

// Round 2
// 3164.214 us; speedup vs baseline: 1.4572x; 1.4572x over previous
//
#include <hip/hip_runtime.h>
#include <cstdint>
#include <cstddef>

typedef unsigned short u16;
typedef __attribute__((ext_vector_type(8))) short short8;
typedef __attribute__((ext_vector_type(4))) float f32x4;

// B=512, T=64, D=16, H=1024 ; 4H=4096
#define NB 512
#define NT 64
#define ND 16
#define NH 1024
#define LDSBUF 12288  // u16 per pipeline buffer: A 64x64 + B 128x64

__device__ __forceinline__ u16 f2bf(float x) {
  union { float f; unsigned u; } v; v.f = x;
  unsigned r = v.u + 0x7fffu + ((v.u >> 16) & 1u);
  return (u16)(r >> 16);
}
__device__ __forceinline__ float sigf(float x) { return 1.f / (1.f + __expf(-x)); }

__device__ __forceinline__ void glds16(const void* g, void* l) {
  __builtin_amdgcn_global_load_lds((const __attribute__((address_space(1))) void*)g,
                                   (__attribute__((address_space(3))) void*)l, 16, 0, 0);
}

// XOR swizzle: 16B-slot ^= (row & 7). Bijective within each 64-col (8-slot) chunk.
__device__ __forceinline__ int swz(int row, int col) {
  return ((((col >> 3) ^ (row & 7)) << 3) | (col & 7));
}

// n' = (h/16)*64 + gate*16 + (h%16)  ->  orig row = gate*1024 + h
__device__ __forceinline__ int inv_np(int np) {
  int hb = np >> 6, g = (np >> 4) & 3, hlo = np & 15;
  return g * 1024 + hb * 16 + hlo;
}

// ---------------- prep: big weight matrices (K=1024) -> bf16 reordered + swizzled ----------------
__global__ void k_prep_big(const float* s0, const float* s1, const float* s2,
                           const float* s3, const float* s4, const float* s5, u16* dst) {
  for (unsigned q = blockIdx.x * 256 + threadIdx.x; q < (6u << 20); q += gridDim.x * 256) {
    int mat = q >> 20;
    int rem = q & ((1 << 20) - 1);
    int np = rem >> 8;            // 0..4095
    int k = (rem & 255) * 4;      // 0..1020, multiple of 4 (stays in one 8-col slot-half)
    int row = inv_np(np);
    const float* s = mat == 0 ? s0 : mat == 1 ? s1 : mat == 2 ? s2 : mat == 3 ? s3 : mat == 4 ? s4 : s5;
    float4 v = *(const float4*)(s + (size_t)row * NH + k);
    u16* d = dst + (size_t)mat * 4194304 + (size_t)np * NH + swz(np, k);
    d[0] = f2bf(v.x); d[1] = f2bf(v.y); d[2] = f2bf(v.z); d[3] = f2bf(v.w);
  }
}

// ---------------- prep: Wih0 padded to K=64 (swizzled), combined biases ----------------
__global__ void k_prep_small(const float* fwih0, const float* bwih0,
                             const float* fbi0, const float* fbh0, const float* fbi1, const float* fbh1,
                             const float* bbi0, const float* bbh0, const float* bbi1, const float* bbh1,
                             u16* wih0p, float* biasb) {
  int idx = blockIdx.x * 256 + threadIdx.x;
  if (idx < 524288) {
    int dir = idx >> 18;
    int r = idx & 262143;
    int np = r >> 6, d = r & 63;
    int row = inv_np(np);
    const float* s = dir ? bwih0 : fwih0;
    float v = (d < 16) ? s[row * 16 + d] : 0.f;
    wih0p[(size_t)dir * 262144 + (size_t)np * 64 + swz(np, d)] = f2bf(v);
  } else if (idx < 524288 + 16384) {
    int j = idx - 524288;
    int which = j >> 12;  // 0 fw-l0, 1 fw-l1, 2 bw-l0, 3 bw-l1
    int np = j & 4095;
    int row = inv_np(np);
    const float* bi = which == 0 ? fbi0 : which == 1 ? fbi1 : which == 2 ? bbi0 : bbi1;
    const float* bh = which == 0 ? fbh0 : which == 1 ? fbh1 : which == 2 ? bbh0 : bbh1;
    biasb[which * 4096 + np] = bi[row] + bh[row];
  }
}

// ---------------- init: pre-loop layer-1 cell from biases; zero layer-0 state ----------------
__global__ void k_init(const float* fbi1, const float* fbh1, const float* bbi1, const float* bbh1,
                       float* c0, float* c1, float* h1f, u16* h0bf, u16* h1bf) {
  int idx = blockIdx.x * 256 + threadIdx.x;  // 2*512*1024 exact
  int dir = idx >> 19;
  int rem = idx & ((1 << 19) - 1);
  int b = rem >> 10, h = rem & 1023;
  const float* bi = dir ? bbi1 : fbi1;
  const float* bh = dir ? bbh1 : fbh1;
  float gi = bi[h] + bh[h];
  float gg = bi[2048 + h] + bh[2048 + h];
  float go = bi[3072 + h] + bh[3072 + h];
  float c = sigf(gi) * tanhf(gg);
  float hv = sigf(go) * tanhf(c);
  size_t o = (size_t)dir * 524288 + rem;
  c1[o] = c;
  h1f[o] = hv;
  h1bf[(size_t)(dir * 2) * 524288 + (size_t)b * NH + swz(b, h)] = f2bf(hv);  // buf 0, swizzled
  c0[o] = 0.f;
  h0bf[(size_t)(dir * 2) * 524288 + rem] = 0;  // zeros: layout-independent
}

// ---------------- cc: (1-m)*(h1 @ out_W^T + out_b) + m*x -> bf16, K padded to 64, swizzled ----------------
__global__ __launch_bounds__(256) void k_cc(const float* values, const float* masks,
                                            const float* outW, const float* outb,
                                            const float* hf1, const float* hb1,
                                            u16* ccbf, int t) {
  int dir = blockIdx.y;
  int w = threadIdx.x >> 6, lane = threadIdx.x & 63;
  int b = blockIdx.x * 4 + w;
  const float* h1 = dir ? hb1 : hf1;
  int tt = dir ? (NT - 1 - t) : t;
  const float4* hrow = (const float4*)(h1 + (size_t)b * NH);
  float4 hv[4];
#pragma unroll
  for (int j = 0; j < 4; ++j) hv[j] = hrow[lane + 64 * j];
  float sums[16];
#pragma unroll
  for (int d = 0; d < 16; ++d) {
    const float4* wrow = (const float4*)(outW + d * NH);
    float s = 0.f;
#pragma unroll
    for (int j = 0; j < 4; ++j) {
      float4 wv = wrow[lane + 64 * j];
      s += hv[j].x * wv.x + hv[j].y * wv.y + hv[j].z * wv.z + hv[j].w * wv.w;
    }
#pragma unroll
    for (int off = 32; off; off >>= 1) s += __shfl_xor(s, off);
    sums[d] = s;
  }
  if (lane == 0) {
    u16* dst = ccbf + ((size_t)dir * 512 + b) * 64;
    const float* xv = values + ((size_t)b * NT + tt) * ND;
    const float* mv = masks + ((size_t)b * NT + tt) * ND;
#pragma unroll
    for (int d = 0; d < 64; ++d) {
      float cc = 0.f;
      if (d < 16) {
        float m = mv[d];
        cc = (1.f - m) * (sums[d] + outb[d]) + m * xv[d];
      }
      dst[swz(b, d)] = f2bf(cc);
    }
  }
}

// ---------------- fused GEMM (2 A/W pairs) + LSTM cell epilogue ----------------
// gates(512x4096, gate-interleaved cols) = A0@W0^T + A1@W1^T + bias; then cell vs c_st.
// 2-deep prefetch pipeline: 3 LDS buffers, counted vmcnt, raw barriers.
struct GemmCellArgs {
  const u16* A0[2]; const u16* W0[2];
  const u16* A1[2]; const u16* W1[2];
  const float* bias[2];
  float* c_st[2];
  float* h_st[2];   // may be null
  u16* h_out[2];
  int nk0;   // chunks (BK=64) in pair 0
  int nk;    // total chunks
  int s1;    // pair-1 row stride (elements)
};

__global__ __launch_bounds__(256) void k_gemm_cell(GemmCellArgs ar) {
  const int dir = blockIdx.z;
  const int tid = threadIdx.x, w = tid >> 6, lane = tid & 63;
  const int m0 = blockIdx.y * 64, n0 = blockIdx.x * 128;

  __shared__ __align__(16) u16 SM[3 * LDSBUF];

  const u16* A0 = ar.A0[dir]; const u16* W0 = ar.W0[dir];
  const u16* A1 = ar.A1[dir]; const u16* W1 = ar.W1[dir];
  const int nk0 = ar.nk0, nk = ar.nk, s1 = ar.s1;

  f32x4 acc[2][4];
#pragma unroll
  for (int i = 0; i < 2; ++i)
#pragma unroll
    for (int j = 0; j < 4; ++j) acc[i][j] = f32x4{0.f, 0.f, 0.f, 0.f};

  const int srow = lane >> 3;        // staging row within 8-row group
  const int scol = (lane & 7) * 8;   // staging col (u16) within 64-col chunk
  const int wm = w >> 1, wn = w & 1;
  const int fr = lane & 15, fq = lane >> 4;
  const int key = fr & 7;
  const int slot0 = (fq ^ key) * 8;        // kk=0 swizzled col (u16)
  const int slot1 = ((fq + 4) ^ key) * 8;  // kk=1

  int aoff[2][2], boff[4][2];
#pragma unroll
  for (int mi = 0; mi < 2; ++mi) {
    int row = wm * 32 + mi * 16 + fr;
    aoff[mi][0] = row * 64 + slot0;
    aoff[mi][1] = row * 64 + slot1;
  }
#pragma unroll
  for (int ni = 0; ni < 4; ++ni) {
    int row = wn * 64 + ni * 16 + fr;
    boff[ni][0] = 4096 + row * 64 + slot0;
    boff[ni][1] = 4096 + row * 64 + slot1;
  }

  auto stage = [&](int c) {
    int buf = c - (c / 3) * 3;
    u16* la = &SM[buf * LDSBUF + (w * 16) * 64];
    u16* lb = &SM[buf * LDSBUF + 4096 + (w * 32) * 64];
    const u16 *pa, *pw; size_t sa, sw;
    if (c < nk0) { pa = A0 + (size_t)c * 64; sa = NH; pw = W0 + (size_t)c * 64; sw = NH; }
    else { pa = A1 + (size_t)(c - nk0) * 64; sa = (size_t)s1; pw = W1 + (size_t)(c - nk0) * 64; sw = (size_t)s1; }
    glds16(pa + (size_t)(m0 + w * 16 + srow) * sa + scol, la);
    glds16(pa + (size_t)(m0 + w * 16 + 8 + srow) * sa + scol, la + 8 * 64);
    glds16(pw + (size_t)(n0 + w * 32 + srow) * sw + scol, lb);
    glds16(pw + (size_t)(n0 + w * 32 + 8 + srow) * sw + scol, lb + 8 * 64);
    glds16(pw + (size_t)(n0 + w * 32 + 16 + srow) * sw + scol, lb + 16 * 64);
    glds16(pw + (size_t)(n0 + w * 32 + 24 + srow) * sw + scol, lb + 24 * 64);
  };

  stage(0);
  stage(1);
  for (int t = 0; t < nk; ++t) {
    if (t + 2 < nk) stage(t + 2);
    // wait for chunk t's 6 loads; keep later chunks in flight (never drain mid-loop)
    if (t + 2 <= nk - 1)      asm volatile("s_waitcnt vmcnt(12)" ::: "memory");
    else if (t == nk - 2)     asm volatile("s_waitcnt vmcnt(6)" ::: "memory");
    else                      asm volatile("s_waitcnt vmcnt(0)" ::: "memory");
    __builtin_amdgcn_s_barrier();
    __builtin_amdgcn_sched_barrier(0);

    int buf = t - (t / 3) * 3;
    const u16* base = &SM[buf * LDSBUF];
    short8 af[2][2], bfr[4][2];
#pragma unroll
    for (int kk = 0; kk < 2; ++kk) {
#pragma unroll
      for (int mi = 0; mi < 2; ++mi) af[mi][kk] = *(const short8*)(base + aoff[mi][kk]);
#pragma unroll
      for (int ni = 0; ni < 4; ++ni) bfr[ni][kk] = *(const short8*)(base + boff[ni][kk]);
    }
#pragma unroll
    for (int kk = 0; kk < 2; ++kk)
#pragma unroll
      for (int mi = 0; mi < 2; ++mi)
#pragma unroll
        for (int ni = 0; ni < 4; ++ni)
          acc[mi][ni] = __builtin_amdgcn_mfma_f32_16x16x32_bf16(af[mi][kk], bfr[ni][kk], acc[mi][ni], 0, 0, 0);

    __builtin_amdgcn_sched_barrier(0);
    __builtin_amdgcn_s_barrier();
  }

  // ---- epilogue: bias + LSTM cell; each (row,h) owned by exactly one lane ----
  const float* bias = ar.bias[dir];
  float* cs = ar.c_st[dir];
  float* hs = ar.h_st[dir];
  u16* ho = ar.h_out[dir];
  const int u = lane & 15;
  const int hg = ((n0 + wn * 64) >> 2) + u;  // hidden unit index
  const float b0 = bias[n0 + wn * 64 + u];
  const float b1 = bias[n0 + wn * 64 + 16 + u];
  const float b2 = bias[n0 + wn * 64 + 32 + u];
  const float b3 = bias[n0 + wn * 64 + 48 + u];
#pragma unroll
  for (int mi = 0; mi < 2; ++mi)
#pragma unroll
    for (int r = 0; r < 4; ++r) {
      int row = m0 + wm * 32 + mi * 16 + ((lane >> 4) << 2) + r;
      size_t sidx = (size_t)row * NH + hg;
      float iv = acc[mi][0][r] + b0;
      float fv = acc[mi][1][r] + b1;
      float gv = acc[mi][2][r] + b2;
      float ov = acc[mi][3][r] + b3;
      float cp = cs[sidx];
      float c2 = sigf(fv) * cp + sigf(iv) * tanhf(gv);
      float hvv = sigf(ov) * tanhf(c2);
      cs[sidx] = c2;
      if (hs) hs[sidx] = hvv;
      ho[(size_t)row * NH + swz(row, hg)] = f2bf(hvv);
    }
}

// ---------------- final outputs ----------------
__global__ void k_final(const float* hf1, const float* hb1, const float* values,
                        const float* masks, float* out) {
  int idx = blockIdx.x * 256 + threadIdx.x;  // 524288 exact
  int b = idx >> 10, j = idx & 1023;
  float hf = hf1[idx];
  float hb = hb1[(size_t)b * NH + (NH - 1 - j)];
  float hv = 0.5f * (hf + hb);
  float m = masks[idx];
  out[idx] = hv;
  out[524288 + idx] = hv;
  out[1048576 + idx] = hv * (1.f - m) + values[idx] * m;
}

extern "C" void kernel_launch(void* const* d_in, const int* in_sizes, int n_in,
                              void* d_out, int out_size, void* d_ws, size_t ws_size,
                              hipStream_t stream) {
  const float* values  = (const float*)d_in[0];
  const float* masks   = (const float*)d_in[1];
  const float* fw_Wih0 = (const float*)d_in[2];
  const float* fw_Whh0 = (const float*)d_in[3];
  const float* fw_bih0 = (const float*)d_in[4];
  const float* fw_bhh0 = (const float*)d_in[5];
  const float* fw_Wih1 = (const float*)d_in[6];
  const float* fw_Whh1 = (const float*)d_in[7];
  const float* fw_bih1 = (const float*)d_in[8];
  const float* fw_bhh1 = (const float*)d_in[9];
  const float* bw_Wih0 = (const float*)d_in[10];
  const float* bw_Whh0 = (const float*)d_in[11];
  const float* bw_bih0 = (const float*)d_in[12];
  const float* bw_bhh0 = (const float*)d_in[13];
  const float* bw_Wih1 = (const float*)d_in[14];
  const float* bw_Whh1 = (const float*)d_in[15];
  const float* bw_bih1 = (const float*)d_in[16];
  const float* bw_bhh1 = (const float*)d_in[17];
  const float* out_W   = (const float*)d_in[18];
  const float* out_b   = (const float*)d_in[19];

  char* ws = (char*)d_ws;
  u16* wbig    = (u16*)ws;                    // 6 x 4M u16 (fwWhh0,fwWih1,fwWhh1,bwWhh0,bwWih1,bwWhh1)
  u16* wih0p   = (u16*)(ws + 50331648);       // 2 x 4096x64 (K padded, swizzled)
  float* biasb = (float*)(ws + 51380224);     // 4 x 4096
  float* c0    = (float*)(ws + 51445760);     // 2 x 512x1024 f32
  float* c1    = (float*)(ws + 55640064);
  float* h1f   = (float*)(ws + 59834368);
  u16* h0bf    = (u16*)(ws + 64028672);       // [dir][pingpong] x 512x1024 bf16 (swizzled)
  u16* h1bf    = (u16*)(ws + 68222976);
  u16* ccbf    = (u16*)(ws + 72417280);       // 2 x 512x64 (swizzled)
  if (ws_size < 72548352) return;

  k_prep_big<<<4096, 256, 0, stream>>>(fw_Whh0, fw_Wih1, fw_Whh1, bw_Whh0, bw_Wih1, bw_Whh1, wbig);
  k_prep_small<<<2112, 256, 0, stream>>>(fw_Wih0, bw_Wih0, fw_bih0, fw_bhh0, fw_bih1, fw_bhh1,
                                         bw_bih0, bw_bhh0, bw_bih1, bw_bhh1, wih0p, biasb);
  k_init<<<4096, 256, 0, stream>>>(fw_bih1, fw_bhh1, bw_bih1, bw_bhh1, c0, c1, h1f, h0bf, h1bf);

  for (int t = 0; t < NT; ++t) {
    int p = t & 1;
    k_cc<<<dim3(128, 2), 256, 0, stream>>>(values, masks, out_W, out_b, h1f, h1f + 524288, ccbf, t);

    GemmCellArgs a0;
    for (int d = 0; d < 2; ++d) {
      a0.A0[d] = h0bf + (size_t)(d * 2 + p) * 524288;
      a0.W0[d] = wbig + (size_t)(d * 3 + 0) * 4194304;
      a0.A1[d] = ccbf + (size_t)d * 32768;
      a0.W1[d] = wih0p + (size_t)d * 262144;
      a0.bias[d] = biasb + (d * 2 + 0) * 4096;
      a0.c_st[d] = c0 + (size_t)d * 524288;
      a0.h_st[d] = nullptr;
      a0.h_out[d] = h0bf + (size_t)(d * 2 + (1 - p)) * 524288;
    }
    a0.nk0 = 16; a0.nk = 17; a0.s1 = 64;
    k_gemm_cell<<<dim3(32, 8, 2), 256, 0, stream>>>(a0);

    GemmCellArgs a1;
    for (int d = 0; d < 2; ++d) {
      a1.A0[d] = h0bf + (size_t)(d * 2 + (1 - p)) * 524288;
      a1.W0[d] = wbig + (size_t)(d * 3 + 1) * 4194304;
      a1.A1[d] = h1bf + (size_t)(d * 2 + p) * 524288;
      a1.W1[d] = wbig + (size_t)(d * 3 + 2) * 4194304;
      a1.bias[d] = biasb + (d * 2 + 1) * 4096;
      a1.c_st[d] = c1 + (size_t)d * 524288;
      a1.h_st[d] = h1f + (size_t)d * 524288;
      a1.h_out[d] = h1bf + (size_t)(d * 2 + (1 - p)) * 524288;
    }
    a1.nk0 = 16; a1.nk = 32; a1.s1 = 1024;
    k_gemm_cell<<<dim3(32, 8, 2), 256, 0, stream>>>(a1);
  }

  k_final<<<2048, 256, 0, stream>>>(h1f, h1f + 524288, values, masks, (float*)d_out);
}